// Round 6
// baseline (402.231 us; speedup 1.0000x reference)
//
#include <hip/hip_runtime.h>

// ============================================================================
// ExtraMHSA pipeline for MI355X (gfx950).  R6: barrier-free epilogues.
//
//   prep_all : pos embeds, BN-fold weights->bf16, zero O/l
//   front_k  : x ->(regs) x1=silu(conv1) ->(LDS) q,k,v,p -> LT/RT/Vv/pT
//   score_k  : computes S^T = (R.L^T) so C-frag cols = i. exp (no-max: scores
//              bounded ~26), rowsum via wave shuffles -> atomic l.
//              C-frag -> pv-A-frag via XOR-16/32 register shuffles (NO LDS
//              round trip, NO epilogue barriers). P stored in [j/32][i/16]
//              tiles of [16 i][32 j], dense 1KB per store instr.
//   pv_k     : O += P.V^T, ZERO LDS / ZERO barriers: P A-frags dense from
//              tiled buffer, V B-frags direct from global (L1-served).
//              fp32 atomicAdd into O.
//   final_k  : out = x + silu(bn(conv2(O1/l1))) + silu(bn(conv3(O2/l2)))
// ============================================================================

typedef unsigned short u16;
typedef __attribute__((ext_vector_type(8))) short bf16x8;   // 8 bf16 = 4 VGPRs
typedef __attribute__((ext_vector_type(4))) float f32x4;    // MFMA C/D frag
typedef __attribute__((ext_vector_type(4))) unsigned int u32x4;

#define HW 6400
#define BN_EPS 1e-5f

__device__ __forceinline__ u16 f2b(float f) {       // fp32 -> bf16 RNE
  unsigned u = __float_as_uint(f);
  u += 0x7fffu + ((u >> 16) & 1u);
  return (u16)(u >> 16);
}
__device__ __forceinline__ unsigned pack2(float a, float b) {
  return (unsigned)f2b(a) | ((unsigned)f2b(b) << 16);
}
__device__ __forceinline__ f32x4 MFMA(bf16x8 a, bf16x8 b, f32x4 c) {
  return __builtin_amdgcn_mfma_f32_16x16x32_bf16(a, b, c, 0, 0, 0);
}
__device__ __forceinline__ float silu_f(float y) {
  return y / (1.0f + __expf(-y));
}
__device__ __forceinline__ bf16x8 pack8(f32x4 lo, f32x4 hi, float sc) {
  union { bf16x8 v; uint4 u; } r;
  r.u.x = pack2(lo[0] * sc, lo[1] * sc);
  r.u.y = pack2(lo[2] * sc, lo[3] * sc);
  r.u.z = pack2(hi[0] * sc, hi[1] * sc);
  r.u.w = pack2(hi[2] * sc, hi[3] * sc);
  return r.v;
}

// ---------------------------------------------------------------------------
// prep_all: [0,80) pos embeds; [80,144) weight BN-fold; [144,176) zero O/l.
// ---------------------------------------------------------------------------
__global__ void prep_all(
    const float* __restrict__ rel_h, const float* __restrict__ rel_w,
    const float* __restrict__ ef_h, const float* __restrict__ ef_w,
    const float* __restrict__ w1, const float* __restrict__ g1, const float* __restrict__ b1,
    const float* __restrict__ m1, const float* __restrict__ v1,
    const float* __restrict__ w2, const float* __restrict__ g2, const float* __restrict__ b2,
    const float* __restrict__ m2, const float* __restrict__ v2,
    const float* __restrict__ w3, const float* __restrict__ g3, const float* __restrict__ b3,
    const float* __restrict__ m3, const float* __restrict__ v3,
    const float* __restrict__ wq, const float* __restrict__ bq,
    const float* __restrict__ wk, const float* __restrict__ bk,
    const float* __restrict__ wv, const float* __restrict__ bv,
    const float* __restrict__ wp, const float* __restrict__ bp,
    u16* __restrict__ LT, u16* __restrict__ efT, u16* __restrict__ efc,
    u16* __restrict__ w1b, float* __restrict__ b1e,
    u16* __restrict__ Wcat, float* __restrict__ bcat,
    u16* __restrict__ w2b, float* __restrict__ b2e,
    u16* __restrict__ w3b, float* __restrict__ b3e,
    float* __restrict__ Obuf, float* __restrict__ lbuf)
{
  const int b = blockIdx.x;
  const int t = threadIdx.x;
  if (b < 80) {
    const int h = b;
    const int c0 = (t & 63) * 2;
    const float rh0 = rel_h[c0 * 80 + h], rh1 = rel_h[(c0 + 1) * 80 + h];
    const float eh0 = ef_h[c0 * 80 + h], eh1 = ef_h[(c0 + 1) * 80 + h];
    for (int wcol = (t >> 6); wcol < 80; wcol += 4) {
      const int i = h * 80 + wcol;
      float rw0 = rel_w[c0 * 80 + wcol], rw1 = rel_w[(c0 + 1) * 80 + wcol];
      float ew0 = ef_w[c0 * 80 + wcol], ew1 = ef_w[(c0 + 1) * 80 + wcol];
      *(unsigned*)&LT[(size_t)i * 256 + 128 + c0] = pack2(rh0 + rw0, rh1 + rw1);
      float e0 = eh0 + ew0, e1 = eh1 + ew1;
      *(unsigned*)&efT[(size_t)i * 128 + c0] = pack2(e0, e1);
      efc[(size_t)c0 * HW + i] = f2b(e0);
      efc[(size_t)(c0 + 1) * HW + i] = f2b(e1);
    }
  } else if (b < 144) {
    const int tid = (b - 80) * 256 + t;
    const int stride = 64 * 256;
    for (int idx = tid; idx < 128 * 256; idx += stride) {
      int o = idx >> 8;
      float s = g1[o] * rsqrtf(v1[o] + BN_EPS);
      w1b[idx] = f2b(w1[idx] * s);
    }
    for (int idx = tid; idx < 128; idx += stride) {
      float s = g1[idx] * rsqrtf(v1[idx] + BN_EPS);
      b1e[idx] = b1[idx] - m1[idx] * s;
    }
    for (int idx = tid; idx < 4 * 128 * 128; idx += stride) {
      int which = idx >> 14, r = idx & 16383;
      const float* src = which == 0 ? wq : which == 1 ? wk : which == 2 ? wv : wp;
      Wcat[idx] = f2b(src[r]);
    }
    for (int idx = tid; idx < 512; idx += stride) {
      int which = idx >> 7, r = idx & 127;
      const float* src = which == 0 ? bq : which == 1 ? bk : which == 2 ? bv : bp;
      bcat[idx] = src[r];
    }
    for (int idx = tid; idx < 256 * 128; idx += stride) {
      int o = idx >> 7;
      float s2 = g2[o] * rsqrtf(v2[o] + BN_EPS);
      w2b[idx] = f2b(w2[idx] * s2);
      float s3 = g3[o] * rsqrtf(v3[o] + BN_EPS);
      w3b[idx] = f2b(w3[idx] * s3);
    }
    for (int idx = tid; idx < 256; idx += stride) {
      float s2 = g2[idx] * rsqrtf(v2[idx] + BN_EPS);
      b2e[idx] = b2[idx] - m2[idx] * s2;
      float s3 = g3[idx] * rsqrtf(v3[idx] + BN_EPS);
      b3e[idx] = b3[idx] - m3[idx] * s3;
    }
  } else {
    const int tid = (b - 144) * 256 + t;
    const int stride = 32 * 256;
    f32x4 z = {0.f, 0.f, 0.f, 0.f};
    for (int idx = tid; idx < 2 * HW * 128 / 4; idx += stride)
      ((f32x4*)Obuf)[idx] = z;
    for (int idx = tid; idx < 2 * HW / 4; idx += stride)
      ((f32x4*)lbuf)[idx] = z;
  }
}

// ---------------------------------------------------------------------------
// front_k: fused  x -> x1=silu(bn(conv1(x))) -> {q,k,v,p} -> LT/RT/Vv/pT.
// grid <<<200, 128>>>: 2 waves x 16 i-rows.
// ---------------------------------------------------------------------------
__global__ __launch_bounds__(128) void front_k(
    const float* __restrict__ x,
    const u16* __restrict__ w1b, const float* __restrict__ b1e,
    const u16* __restrict__ Wcat, const float* __restrict__ bcat,
    u16* __restrict__ LT, u16* __restrict__ RT, u16* __restrict__ Vv,
    u16* __restrict__ pT)
{
  __shared__ __align__(16) u16 tr[2][16][136];
  const int t = threadIdx.x, w = t >> 6, lane = t & 63, jl = lane & 15, q = lane >> 4;
  const int i0 = blockIdx.x * 32 + w * 16;

  // ---- x A-fragments (k = channel d), built from strided fp32 loads
  bf16x8 afr[8];
#pragma unroll
  for (int ks = 0; ks < 8; ++ks) {
    union { bf16x8 v; u16 e[8]; } fa;
#pragma unroll
    for (int e = 0; e < 8; ++e)
      fa.e[e] = f2b(x[(size_t)(ks * 32 + q * 8 + e) * HW + i0 + jl]);
    afr[ks] = fa.v;
  }
  // ---- x1 = silu(x . w1b + b1e)
  f32x4 acc[8];
#pragma unroll
  for (int nf = 0; nf < 8; ++nf) acc[nf] = (f32x4){0.f, 0.f, 0.f, 0.f};
#pragma unroll
  for (int ks = 0; ks < 8; ++ks)
#pragma unroll
    for (int nf = 0; nf < 8; ++nf) {
      bf16x8 b = *(const bf16x8*)(w1b + (size_t)(nf * 16 + jl) * 256 + ks * 32 + q * 8);
      acc[nf] = MFMA(afr[ks], b, acc[nf]);
    }
#pragma unroll
  for (int nf = 0; nf < 8; ++nf) {
    const int c = nf * 16 + jl;
    const float bias = b1e[c];
#pragma unroll
    for (int r = 0; r < 4; ++r)
      tr[w][q * 4 + r][c] = f2b(silu_f(acc[nf][r] + bias));
  }
  __syncthreads();                               // x1 writes -> xa reads
  bf16x8 xa[4];
#pragma unroll
  for (int ks = 0; ks < 4; ++ks)
    xa[ks] = *(const bf16x8*)&tr[w][jl][ks * 32 + q * 8];

  // ---- q,k,v,p projections
#pragma unroll
  for (int nc = 0; nc < 4; ++nc) {
    f32x4 a2[8];
#pragma unroll
    for (int nf = 0; nf < 8; ++nf) a2[nf] = (f32x4){0.f, 0.f, 0.f, 0.f};
#pragma unroll
    for (int ks = 0; ks < 4; ++ks)
#pragma unroll
      for (int nf = 0; nf < 8; ++nf) {
        bf16x8 b = *(const bf16x8*)(Wcat + (size_t)(nc * 128 + nf * 16 + jl) * 128 + ks * 32 + q * 8);
        a2[nf] = MFMA(xa[ks], b, a2[nf]);
      }
    if (nc == 2) {                               // V: [c][i] direct store
#pragma unroll
      for (int nf = 0; nf < 8; ++nf) {
        const int c = nf * 16 + jl;
        const float bias = bcat[256 + c];
        uint2 pk;
        pk.x = pack2(a2[nf][0] + bias, a2[nf][1] + bias);
        pk.y = pack2(a2[nf][2] + bias, a2[nf][3] + bias);
        *(uint2*)(Vv + (size_t)c * HW + i0 + q * 4) = pk;
      }
    } else {
      __syncthreads();                           // prev reads done -> overwrite
#pragma unroll
      for (int nf = 0; nf < 8; ++nf) {
        const int c = nf * 16 + jl;
        const float bias = bcat[nc * 128 + c];
#pragma unroll
        for (int r = 0; r < 4; ++r)
          tr[w][q * 4 + r][c] = f2b(a2[nf][r] + bias);
      }
      __syncthreads();                           // writes -> row reads
#pragma unroll
      for (int r = 0; r < 16; ++r) {
        unsigned val = *(const unsigned*)&tr[w][r][lane * 2];
        const size_t row = (size_t)(i0 + r);
        if (nc == 0) {
          *(unsigned*)(LT + row * 256 + lane * 2) = val;
          *(unsigned*)(RT + row * 256 + 128 + lane * 2) = val;
        } else if (nc == 1) {
          *(unsigned*)(RT + row * 256 + lane * 2) = val;
        } else {
          *(unsigned*)(pT + row * 128 + lane * 2) = val;
        }
      }
    }
  }
}

// ---------------------------------------------------------------------------
// score_k: S^T GEMM (A = R rows = j, B = L rows = i staged in LDS).
// C-frag: col = i_loc = nf*16+jl, row = j_loc = mt*16+q*4+r.
// Epilogue: exp in regs, rowsum + C->A-frag transform via XOR shuffles,
// dense tiled stores. NO epilogue barriers, NO LDS round trip.
// Tiled P: tile (jc=j/32, i16=i/16) of 512 elems [16 i][32 j] row-major.
// grid <<<2500, 256>>>.
// ---------------------------------------------------------------------------
template <int KD, int MINB>
__global__ __launch_bounds__(256, MINB) void score_k(
    const u16* __restrict__ Rt,     // [HW][KD]  j-side (A)
    const u16* __restrict__ Lt,     // [HW][KD]  i-side (B, staged)
    u16* __restrict__ P,            // tiled
    float* __restrict__ lv)         // [HW]
{
  __shared__ __align__(16) u16 Bs[128 * KD];     // 64KB (KD=256) / 32KB (128)
  const int t = threadIdx.x, w = t >> 6, lane = t & 63, jl = lane & 15, q = lane >> 4;
  const int it = blockIdx.x / 50, jt = blockIdx.x % 50;
  const int i0B = it * 128;                      // B-side base (i)
  const int j0W = jt * 128 + w * 32;             // this wave's j base (A-side)
  constexpr int NKS = KD / 32;

  // A fragments (R rows = j) resident in registers: 2 m-tiles x K
  bf16x8 afr[2][NKS];
#pragma unroll
  for (int mt = 0; mt < 2; ++mt)
#pragma unroll
    for (int ks = 0; ks < NKS; ++ks)
      afr[mt][ks] = *(const bf16x8*)(Rt + (size_t)(j0W + mt * 16 + jl) * KD + ks * 32 + q * 8);

  // Stage B tile = L rows [128 i][KD], XOR-8 16B-chunk swizzle
  if constexpr (KD == 256) {
#pragma unroll
    for (int cc = 0; cc < 16; ++cc) {
      int jr = w * 32 + cc * 2 + (lane >> 5);
      int cp = lane & 31;
      int ch = (cp & ~7) | ((cp ^ jr) & 7);
      *(u32x4*)(Bs + jr * 256 + cp * 8) =
          *(const u32x4*)(Lt + (size_t)(i0B + jr) * 256 + ch * 8);
    }
  } else {
#pragma unroll
    for (int cc = 0; cc < 8; ++cc) {
      int jr = w * 32 + cc * 4 + (lane >> 4);
      int cp = lane & 15;
      int ch = (cp & ~7) | ((cp ^ jr) & 7);
      *(u32x4*)(Bs + jr * 128 + cp * 8) =
          *(const u32x4*)(Lt + (size_t)(i0B + jr) * 128 + ch * 8);
    }
  }
  __syncthreads();                               // the ONLY barrier

  f32x4 s[2][8];
#pragma unroll
  for (int mt = 0; mt < 2; ++mt)
#pragma unroll
    for (int nf = 0; nf < 8; ++nf) s[mt][nf] = (f32x4){0.f, 0.f, 0.f, 0.f};

#pragma unroll
  for (int nf = 0; nf < 8; ++nf) {
    const int row = nf * 16 + jl;
#pragma unroll
    for (int ks = 0; ks < NKS; ++ks) {
      const int ch = (ks * 4 + q) ^ (jl & 7);    // un-swizzle
      bf16x8 b = *(const bf16x8*)(Bs + row * KD + ch * 8);
      s[0][nf] = MFMA(afr[0][ks], b, s[0][nf]);
      s[1][nf] = MFMA(afr[1][ks], b, s[1][nf]);
    }
  }

  // ---- epilogue: barrier-free
  const int jc32 = jt * 4 + w;                   // this wave's 32-j tile index
  const int it8 = it * 8;
#pragma unroll
  for (int nf = 0; nf < 8; ++nf) {
    f32x4 e0, e1;
#pragma unroll
    for (int r = 0; r < 4; ++r) {
      e0[r] = __expf(s[0][nf][r]);
      e1[r] = __expf(s[1][nf][r]);
    }
    // row-sum over this wave's 32 j for col i = i0B + nf*16 + jl
    float sm = e0[0] + e0[1] + e0[2] + e0[3] + e1[0] + e1[1] + e1[2] + e1[3];
    sm += __shfl_xor(sm, 16);
    sm += __shfl_xor(sm, 32);
    if (q == 0) atomicAdd(&lv[i0B + nf * 16 + jl], sm);
    // pack own 4+4 j's to bf16
    unsigned t0x = pack2(e0[0], e0[1]), t0y = pack2(e0[2], e0[3]);
    unsigned t1x = pack2(e1[0], e1[1]), t1y = pack2(e1[2], e1[3]);
    // quad-pair exchange (xor 16): build 8-j halves
    unsigned u0x = __shfl_xor(t0x, 16), u0y = __shfl_xor(t0y, 16);
    unsigned u1x = __shfl_xor(t1x, 16), u1y = __shfl_xor(t1y, 16);
    u32x4 c0 = (q & 1) ? (u32x4){u0x, u0y, t0x, t0y} : (u32x4){t0x, t0y, u0x, u0y};
    u32x4 c1 = (q & 1) ? (u32x4){u1x, u1y, t1x, t1y} : (u32x4){t1x, t1y, u1x, u1y};
    // cross exchange (xor 32): each lane fetches the one half it lacks
    u32x4 snd = (q & 2) ? c0 : c1;
    u32x4 rcv;
    rcv.x = __shfl_xor(snd.x, 32);
    rcv.y = __shfl_xor(snd.y, 32);
    rcv.z = __shfl_xor(snd.z, 32);
    rcv.w = __shfl_xor(snd.w, 32);
    u32x4 af = (q == 0) ? c0 : (q == 3) ? c1 : rcv;
    // dense tiled store: 64 lanes cover the 1KB tile contiguously
    *(u32x4*)(P + ((size_t)jc32 * 400 + it8 + nf) * 512 + jl * 32 + q * 8) = af;
  }
}

// ---------------------------------------------------------------------------
// pv_k: O[i][c] += P . V^T.  ZERO LDS, ZERO barriers: pure streaming.
// Block = 128i x 128c x 640j (jp 0..9); waves split i (32 each).
// A-frags dense from tiled P; V B-frags direct from global (L1-served).
// grid <<<500, 256>>>.
// ---------------------------------------------------------------------------
__global__ __launch_bounds__(256, 2) void pv_k(
    const u16* __restrict__ Pt,     // tiled P
    const u16* __restrict__ Vm,     // [128][HW]
    float* __restrict__ O)          // [HW][128]
{
  const int t = threadIdx.x, w = t >> 6, lane = t & 63, jl = lane & 15, q = lane >> 4;
  const int it = blockIdx.x / 10, jp = blockIdx.x % 10;
  const int it16 = it * 8 + w * 2;

  f32x4 o[2][8];
#pragma unroll
  for (int mt = 0; mt < 2; ++mt)
#pragma unroll
    for (int cf = 0; cf < 8; ++cf) o[mt][cf] = (f32x4){0.f, 0.f, 0.f, 0.f};

  for (int jc = jp * 20; jc < jp * 20 + 20; ++jc) {
    const int j0 = jc * 32;
    const size_t pb = ((size_t)jc * 400 + it16) * 512 + jl * 32 + q * 8;
    bf16x8 a0 = *(const bf16x8*)(Pt + pb);
    bf16x8 a1 = *(const bf16x8*)(Pt + pb + 512);
#pragma unroll
    for (int cf = 0; cf < 8; ++cf) {
      bf16x8 b = *(const bf16x8*)(Vm + (size_t)(cf * 16 + jl) * HW + j0 + q * 8);
      o[0][cf] = MFMA(a0, b, o[0][cf]);
      o[1][cf] = MFMA(a1, b, o[1][cf]);
    }
  }
  // atomic accumulate into O (L2-resident, 3.3 MB)
#pragma unroll
  for (int mt = 0; mt < 2; ++mt) {
    const int ib = it * 128 + w * 32 + mt * 16 + q * 4;
#pragma unroll
    for (int cf = 0; cf < 8; ++cf) {
      const int c = cf * 16 + jl;
#pragma unroll
      for (int r = 0; r < 4; ++r)
        atomicAdd(&O[(size_t)(ib + r) * 128 + c], o[mt][cf][r]);
    }
  }
}

// ---------------------------------------------------------------------------
// final_k: out[d][i] = x[d][i] + silu(o1.w2b + b2e) + silu(o2.w3b + b3e),
// o?[i][c] = O[h][i][c] / l[h][i], built as bf16 A-frags on the fly.
// grid dim3(100, 2), 256 thr.
// ---------------------------------------------------------------------------
__global__ __launch_bounds__(256) void final_k(
    const float* __restrict__ Obuf,    // [2][HW][128]
    const float* __restrict__ lbuf,    // [2][HW]
    const u16* __restrict__ w2b, const float* __restrict__ b2e,
    const u16* __restrict__ w3b, const float* __restrict__ b3e,
    const float* __restrict__ x, float* __restrict__ outp)
{
  const int t = threadIdx.x, w = t >> 6, lane = t & 63, jl = lane & 15, q = lane >> 4;
  const int i0 = blockIdx.x * 64 + w * 16;
  const int nc = blockIdx.y;
  const int row = i0 + jl;

  const float inv1 = 1.0f / lbuf[row];
  const float inv2 = 1.0f / lbuf[HW + row];
  const float* O1 = Obuf + (size_t)row * 128;
  const float* O2 = Obuf + (size_t)(HW + row) * 128;

  f32x4 a1[8], a2[8];
#pragma unroll
  for (int nf = 0; nf < 8; ++nf) {
    a1[nf] = (f32x4){0.f, 0.f, 0.f, 0.f};
    a2[nf] = (f32x4){0.f, 0.f, 0.f, 0.f};
  }
#pragma unroll
  for (int ks = 0; ks < 4; ++ks) {
    f32x4 s1a = *(const f32x4*)(O1 + ks * 32 + q * 8);
    f32x4 s1b = *(const f32x4*)(O1 + ks * 32 + q * 8 + 4);
    f32x4 s2a = *(const f32x4*)(O2 + ks * 32 + q * 8);
    f32x4 s2b = *(const f32x4*)(O2 + ks * 32 + q * 8 + 4);
    bf16x8 fa1 = pack8(s1a, s1b, inv1);
    bf16x8 fa2 = pack8(s2a, s2b, inv2);
#pragma unroll
    for (int nf = 0; nf < 8; ++nf) {
      bf16x8 b2f = *(const bf16x8*)(w2b + (size_t)(nc * 128 + nf * 16 + jl) * 128 + ks * 32 + q * 8);
      bf16x8 b3f = *(const bf16x8*)(w3b + (size_t)(nc * 128 + nf * 16 + jl) * 128 + ks * 32 + q * 8);
      a1[nf] = MFMA(fa1, b2f, a1[nf]);
      a2[nf] = MFMA(fa2, b3f, a2[nf]);
    }
  }
#pragma unroll
  for (int nf = 0; nf < 8; ++nf) {
    const int d = nc * 128 + nf * 16 + jl;
    const float bb2 = b2e[d], bb3 = b3e[d];
    const size_t base = (size_t)d * HW + i0 + q * 4;
    f32x4 xv = *(const f32x4*)(x + base);
    f32x4 rv;
#pragma unroll
    for (int r = 0; r < 4; ++r)
      rv[r] = xv[r] + silu_f(a1[nf][r] + bb2) + silu_f(a2[nf][r] + bb3);
    *(f32x4*)(outp + base) = rv;
  }
}

// ---------------------------------------------------------------------------
extern "C" void kernel_launch(void* const* d_in, const int* in_sizes, int n_in,
                              void* d_out, int out_size, void* d_ws, size_t ws_size,
                              hipStream_t stream)
{
  (void)in_sizes; (void)n_in; (void)out_size; (void)ws_size;
  const float* x   = (const float*)d_in[0];
  const float* w1  = (const float*)d_in[1];
  const float* g1  = (const float*)d_in[2];
  const float* b1  = (const float*)d_in[3];
  const float* m1  = (const float*)d_in[4];
  const float* v1  = (const float*)d_in[5];
  const float* w2  = (const float*)d_in[6];
  const float* g2  = (const float*)d_in[7];
  const float* b2  = (const float*)d_in[8];
  const float* m2  = (const float*)d_in[9];
  const float* v2  = (const float*)d_in[10];
  const float* w3  = (const float*)d_in[11];
  const float* g3  = (const float*)d_in[12];
  const float* b3  = (const float*)d_in[13];
  const float* m3  = (const float*)d_in[14];
  const float* v3  = (const float*)d_in[15];
  const float* wq  = (const float*)d_in[16];
  const float* bq  = (const float*)d_in[17];
  const float* wk  = (const float*)d_in[18];
  const float* bk  = (const float*)d_in[19];
  const float* wv  = (const float*)d_in[20];
  const float* bv  = (const float*)d_in[21];
  const float* wp  = (const float*)d_in[22];
  const float* bp  = (const float*)d_in[23];
  const float* rel_h = (const float*)d_in[24];
  const float* rel_w = (const float*)d_in[25];
  const float* ef_h  = (const float*)d_in[26];
  const float* ef_w  = (const float*)d_in[27];
  float* outp = (float*)d_out;

  char* ws = (char*)d_ws;
  size_t off = 0;
  auto alloc = [&](size_t bytes) -> void* {
    void* p = ws + off;
    off += (bytes + 511) & ~(size_t)511;
    return p;
  };
  u16* LT    = (u16*)alloc((size_t)HW * 256 * 2);
  u16* RT    = (u16*)alloc((size_t)HW * 256 * 2);
  u16* pT    = (u16*)alloc((size_t)HW * 128 * 2);
  u16* efT   = (u16*)alloc((size_t)HW * 128 * 2);
  u16* efc   = (u16*)alloc((size_t)HW * 128 * 2);
  u16* Vv    = (u16*)alloc((size_t)HW * 128 * 2);
  u16* Pbuf  = (u16*)alloc((size_t)HW * HW * 2);            // 81.9 MB (tiled)
  float* Obuf = (float*)alloc((size_t)2 * HW * 128 * 4);    // 6.55 MB
  float* lbuf = (float*)alloc((size_t)2 * HW * 4);
  u16* w1b   = (u16*)alloc(128 * 256 * 2);
  float* b1e = (float*)alloc(128 * 4);
  u16* Wcat  = (u16*)alloc(512 * 128 * 2);
  float* bcat = (float*)alloc(512 * 4);
  u16* w2b   = (u16*)alloc(256 * 128 * 2);
  float* b2e = (float*)alloc(256 * 4);
  u16* w3b   = (u16*)alloc(256 * 128 * 2);
  float* b3e = (float*)alloc(256 * 4);

  prep_all<<<176, 256, 0, stream>>>(rel_h, rel_w, ef_h, ef_w,
                                    w1, g1, b1, m1, v1, w2, g2, b2, m2, v2,
                                    w3, g3, b3, m3, v3, wq, bq, wk, bk, wv, bv, wp, bp,
                                    LT, efT, efc,
                                    w1b, b1e, Wcat, bcat, w2b, b2e, w3b, b3e,
                                    Obuf, lbuf);
  front_k<<<200, 128, 0, stream>>>(x, w1b, b1e, Wcat, bcat, LT, RT, Vv, pT);
  // head 1: A = RT (k|q concat, j-side), B = LT (q|pos concat, i-side)
  score_k<256, 2><<<2500, 256, 0, stream>>>(RT, LT, Pbuf, lbuf);
  pv_k<<<500, 256, 0, stream>>>(Pbuf, Vv, Obuf);
  // head 2 (reuses Pbuf): A = efT (j-side), B = pT (i-side)
  score_k<128, 3><<<2500, 256, 0, stream>>>(efT, pT, Pbuf, lbuf + HW);
  pv_k<<<500, 256, 0, stream>>>(Pbuf, efc, Obuf + (size_t)HW * 128);
  final_k<<<dim3(100, 2), 256, 0, stream>>>(Obuf, lbuf, w2b, b2e, w3b, b3e, x, outp);
}